// Round 7
// baseline (739.930 us; speedup 1.0000x reference)
//
#include <hip/hip_runtime.h>
#include <hip/hip_bf16.h>

#define N_NODES 50000
#define NREL 16
#define HID 64
#define NCLS 16
#define NBKT (N_NODES * NREL)       // 800000 buckets (dst*16 + rel)
#define SB 2048                     // scan elems per block
#define NSB ((NBKT + SB - 1) / SB)  // 391
#define TILE 16                     // dst nodes per fused block (50000/16 exact)
#define NTB (N_NODES / TILE)        // 3125
#define XCHUNKS (N_NODES * HID / 8) // 400000
#define W1N (17 * HID * HID)        // 69632
#define W2N (17 * NCLS * HID)       // 17408
#define ROWW 68                     // f32 row stride: 16B-aligned (272B), bank-rotating

typedef __attribute__((ext_vector_type(8))) short bf16x8;
typedef __attribute__((ext_vector_type(4))) float f32x4;

static __device__ __forceinline__ unsigned short f2bf(float f) {
    __hip_bfloat16 h = __float2bfloat16(f);
    return *reinterpret_cast<unsigned short*>(&h);
}
static __device__ __forceinline__ float bf2f(unsigned short u) {
    __hip_bfloat16 h;
    *reinterpret_cast<unsigned short*>(&h) = u;
    return __bfloat162float(h);
}

// ---------------------------------------------------------------------------
// ws layout:
//   bcnt/rstart i32[800020] (zeroed; scan3 -> prefix IN PLACE)
//   | rank i32[E] | bsum i32[512] | sedge i32[E] (src | rel<<16 | (dst&15)<<20)
//   | WbT1 bf16[17*64*64] [t][n][k] | WbT2 bf16[17*16*64] [t][n][k]
//   | xb bf16[50000*64] | X1b bf16[50000*64]
// Fused layers: per 16-node tile, edge-PARALLEL gather with NATIVE
// ds_add_f32 (inline asm — HIP's atomicAdd on LDS floats lowers to a CAS
// retry loop, the round-4 disaster). Then MFMA with on-the-fly mean-scale
// + bf16 convert of A-fragments (round-4's verified path).
// ---------------------------------------------------------------------------

// K0: merged rank (bucket count + per-edge rank) and cvt (x->bf16, weightsT)
__global__ __launch_bounds__(256) void pre_k(const int* __restrict__ dstp,
                                             const int* __restrict__ et,
                                             int* __restrict__ bcnt,
                                             int* __restrict__ rank, int E,
                                             const float* __restrict__ x,
                                             const float* __restrict__ W1,
                                             const float* __restrict__ root1,
                                             const float* __restrict__ W2,
                                             const float* __restrict__ root2,
                                             ushort* __restrict__ xb,
                                             ushort* __restrict__ WbT1,
                                             ushort* __restrict__ WbT2) {
    int eb = (E + 255) >> 8;
    if ((int)blockIdx.x < eb) {
        int i = blockIdx.x * 256 + threadIdx.x;
        if (i < E) {
            int b = dstp[i] * NREL + et[i];
            rank[i] = atomicAdd(&bcnt[b], 1);
        }
        return;
    }
    int i = (blockIdx.x - eb) * 256 + threadIdx.x;
    if (i < XCHUNKS) {
        float4 f0 = *(const float4*)(x + (size_t)i * 8);
        float4 f1 = *(const float4*)(x + (size_t)i * 8 + 4);
        bf16x8 o;
        o[0] = (short)f2bf(f0.x); o[1] = (short)f2bf(f0.y);
        o[2] = (short)f2bf(f0.z); o[3] = (short)f2bf(f0.w);
        o[4] = (short)f2bf(f1.x); o[5] = (short)f2bf(f1.y);
        o[6] = (short)f2bf(f1.z); o[7] = (short)f2bf(f1.w);
        *(bf16x8*)(xb + (size_t)i * 8) = o;
    } else {
        int j = i - XCHUNKS;
        if (j < W1N) {
            int t = j >> 12, rem = j & 4095, n = rem >> 6, k = rem & 63;
            float v = (t < 16) ? W1[(size_t)t * HID * HID + k * HID + n]
                               : root1[k * HID + n];
            WbT1[j] = f2bf(v);
        } else {
            int m = j - W1N;
            if (m < W2N) {
                int t = m >> 10, rem = m & 1023, n = rem >> 6, k = rem & 63;
                float v = (t < 16) ? W2[(size_t)t * HID * NCLS + k * NCLS + n]
                                   : root2[k * NCLS + n];
                WbT2[m] = f2bf(v);
            }
        }
    }
}

// K2a: per-block sums of bcnt (2048 elems / block, 8 per thread)
__global__ __launch_bounds__(256) void scan1_k(const int* __restrict__ bcnt,
                                               int* __restrict__ bsum) {
    int b = blockIdx.x, t = threadIdx.x;
    int base = b * SB + t * 8;
    int s = 0;
#pragma unroll
    for (int j = 0; j < 8; ++j)
        if (base + j < NBKT) s += bcnt[base + j];
#pragma unroll
    for (int off = 1; off < 64; off <<= 1) s += __shfl_xor(s, off, 64);
    __shared__ int ws[4];
    if ((t & 63) == 0) ws[t >> 6] = s;
    __syncthreads();
    if (t == 0) bsum[b] = ws[0] + ws[1] + ws[2] + ws[3];
}

// K2b: exclusive scan of bsum[NSB] (one 512-thread block); rstart[NBKT] = E
__global__ __launch_bounds__(512) void scan2_k(int* __restrict__ bsum,
                                               int* __restrict__ rstart, int E) {
    __shared__ int ts[512];
    int t = threadIdx.x;
    int v = (t < NSB) ? bsum[t] : 0;
    ts[t] = v;
    __syncthreads();
    int acc = v;
    for (int off = 1; off < 512; off <<= 1) {
        int u = (t >= off) ? ts[t - off] : 0;
        __syncthreads();
        acc += u;
        ts[t] = acc;
        __syncthreads();
    }
    if (t < NSB) bsum[t] = acc - v;
    if (t == 0) rstart[NBKT] = E;
}

// K2c: per-block exclusive scan, IN PLACE (bcnt -> rstart)
__global__ __launch_bounds__(256) void scan3_k(int* __restrict__ bcnt,
                                               const int* __restrict__ bsum) {
    int b = blockIdx.x, t = threadIdx.x;
    int base = b * SB + t * 8;
    int a[8];
    int s = 0;
#pragma unroll
    for (int j = 0; j < 8; ++j) {
        a[j] = (base + j < NBKT) ? bcnt[base + j] : 0;
        s += a[j];
    }
    __shared__ int ts[256];
    ts[t] = s;
    __syncthreads();
    int acc = s;
    for (int off = 1; off < 256; off <<= 1) {
        int u = (t >= off) ? ts[t - off] : 0;
        __syncthreads();
        acc += u;
        ts[t] = acc;
        __syncthreads();
    }
    int run = bsum[b] + (acc - s);
#pragma unroll
    for (int j = 0; j < 8; ++j) {
        if (base + j < NBKT) bcnt[base + j] = run;
        run += a[j];
    }
}

// K3: atomic-free scatter; pack src | rel<<16 | (dst&15)<<20
__global__ __launch_bounds__(256) void scat_k(const int* __restrict__ srcp,
                                              const int* __restrict__ dstp,
                                              const int* __restrict__ et,
                                              const int* __restrict__ rank,
                                              const int* __restrict__ rstart,
                                              int* __restrict__ sedge, int E) {
    int i = blockIdx.x * 256 + threadIdx.x;
    if (i < E) {
        int r = et[i];
        int d = dstp[i];
        int b = d * NREL + r;
        sedge[rstart[b] + rank[i]] = srcp[i] | (r << 16) | ((d & 15) << 20);
    }
}

// ---------------------------------------------------------------------------
// Edge-parallel gather: 32 groups x 8 lanes; edge e = lo + round*32 + g
// (coalesced descriptors, counts per group differ by <=1). Lane l8 owns
// feature bytes [l8*16, l8*16+16) and issues 8 native ds_add_f32 (one base
// addr + offset:q*4). No result, no retry -> loads pipeline freely.
// ---------------------------------------------------------------------------
#define DSADD(OFF, V) \
    asm volatile("ds_add_f32 %0, %1 offset:" #OFF :: "v"(a), "v"(V))

static __device__ __forceinline__ void gather_acc(unsigned accBase,
                                                  const ushort* __restrict__ ft,
                                                  const int* __restrict__ sedge,
                                                  int lo, int hi, int tid) {
    int g = tid >> 3, l8 = tid & 7;
    const ushort* xcol = ft + l8 * 8;
    int e = lo + g;
    if (e >= hi) return;
    int d = sedge[e];
    bf16x8 f = *(const bf16x8*)(xcol + (size_t)(d & 0xFFFF) * HID);
    while (true) {
        int e2 = e + 32;
        bool more = e2 < hi;
        int d2 = 0;
        bf16x8 f2 = {0, 0, 0, 0, 0, 0, 0, 0};
        if (more) {
            d2 = sedge[e2];
            f2 = *(const bf16x8*)(xcol + (size_t)(d2 & 0xFFFF) * HID);
        }
        unsigned row = (unsigned)((((d >> 16) & 15) * TILE) + ((d >> 20) & 15));
        unsigned a = accBase + (row * ROWW + (unsigned)l8 * 8) * 4;
        float v0 = bf2f((unsigned short)f[0]);
        float v1 = bf2f((unsigned short)f[1]);
        float v2 = bf2f((unsigned short)f[2]);
        float v3 = bf2f((unsigned short)f[3]);
        float v4 = bf2f((unsigned short)f[4]);
        float v5 = bf2f((unsigned short)f[5]);
        float v6 = bf2f((unsigned short)f[6]);
        float v7 = bf2f((unsigned short)f[7]);
        DSADD(0, v0);
        DSADD(4, v1);
        DSADD(8, v2);
        DSADD(12, v3);
        DSADD(16, v4);
        DSADD(20, v5);
        DSADD(24, v6);
        DSADD(28, v7);
        if (!more) break;
        e = e2;
        d = d2;
        f = f2;
    }
}

// Load+scale+convert one A-fragment pair from f32 LDS (round-4 verified).
#define LOAD_A(T)                                                             \
    const float* arow_ = Acc + ((T)*TILE + mr) * ROWW + kq * 8;               \
    float inv_ = InvL[(T)*TILE + mr];                                         \
    f32x4 v0_ = *(const f32x4*)(arow_);                                       \
    f32x4 v1_ = *(const f32x4*)(arow_ + 4);                                   \
    f32x4 v2_ = *(const f32x4*)(arow_ + 32);                                  \
    f32x4 v3_ = *(const f32x4*)(arow_ + 36);                                  \
    bf16x8 a0, a1;                                                            \
    _Pragma("unroll") for (int j_ = 0; j_ < 4; ++j_) {                        \
        a0[j_] = (short)f2bf(v0_[j_] * inv_);                                 \
        a0[j_ + 4] = (short)f2bf(v1_[j_] * inv_);                             \
        a1[j_] = (short)f2bf(v2_[j_] * inv_);                                 \
        a1[j_ + 4] = (short)f2bf(v3_[j_] * inv_);                             \
    }

__global__ __launch_bounds__(256) void fuse1_k(const ushort* __restrict__ xb,
                                               const int* __restrict__ sedge,
                                               const int* __restrict__ rstart,
                                               const ushort* __restrict__ WbT1,
                                               const float* __restrict__ b1,
                                               ushort* __restrict__ X1b) {
    __shared__ __align__(16) float Acc[NREL * TILE * ROWW];  // 69632 B
    __shared__ float InvL[NREL * TILE];                      // 1024 B
    int tid = threadIdx.x;
    int dst0 = blockIdx.x * TILE;
    int wave = tid >> 6, lane = tid & 63;
    int mr = lane & 15, kq = lane >> 4;

    // root A-frags straight from global (prefetch early)
    const ushort* xrow = xb + (size_t)(dst0 + mr) * HID + kq * 8;
    bf16x8 ra0 = *(const bf16x8*)(xrow);
    bf16x8 ra1 = *(const bf16x8*)(xrow + 32);

    // inverse counts (rstart diffs, coalesced)
    {
        int n = tid >> 4, r = tid & 15;
        int b = (dst0 + n) * NREL + r;
        int c0 = rstart[b], c1 = rstart[b + 1];
        InvL[r * TILE + n] = (c1 > c0) ? 1.0f / (float)(c1 - c0) : 0.0f;
    }
    // zero accumulators: thread t owns row t (68 f32 = 17 x f32x4)
    {
        float* rowp = Acc + tid * ROWW;
        f32x4 z = {0.f, 0.f, 0.f, 0.f};
#pragma unroll
        for (int i = 0; i < 17; ++i) *(f32x4*)(rowp + i * 4) = z;
    }
    int lo = rstart[dst0 * NREL];
    int hi = rstart[(dst0 + TILE) * NREL];
    __syncthreads();

    unsigned accBase = (unsigned)(unsigned long long)(void*)Acc;
    gather_acc(accBase, xb, sedge, lo, hi, tid);
    asm volatile("s_waitcnt lgkmcnt(0)" ::: "memory");  // asm DS ops untracked
    __syncthreads();

    // MFMA: wave w owns out cols [w*16, w*16+16); A = 16 nodes x 64
    const ushort* wb = WbT1 + (wave * 16 + mr) * HID + kq * 8;
    f32x4 c = {0.f, 0.f, 0.f, 0.f};
    bf16x8 bk0 = *(const bf16x8*)(wb);
    bf16x8 bk1 = *(const bf16x8*)(wb + 32);
    for (int t = 0; t < 16; ++t) {
        bf16x8 nb0 = *(const bf16x8*)(wb + (t + 1) * (HID * HID));
        bf16x8 nb1 = *(const bf16x8*)(wb + (t + 1) * (HID * HID) + 32);
        LOAD_A(t)
        c = __builtin_amdgcn_mfma_f32_16x16x32_bf16(a0, bk0, c, 0, 0, 0);
        c = __builtin_amdgcn_mfma_f32_16x16x32_bf16(a1, bk1, c, 0, 0, 0);
        bk0 = nb0;
        bk1 = nb1;
    }
    // root (bk now holds t=16 fragments)
    c = __builtin_amdgcn_mfma_f32_16x16x32_bf16(ra0, bk0, c, 0, 0, 0);
    c = __builtin_amdgcn_mfma_f32_16x16x32_bf16(ra1, bk1, c, 0, 0, 0);

    float bias = b1[wave * 16 + mr];
    int col = wave * 16 + mr;
#pragma unroll
    for (int j = 0; j < 4; ++j) {
        int node = dst0 + kq * 4 + j;  // D row = quad*4+reg
        X1b[(size_t)node * HID + col] = f2bf(fmaxf(c[j] + bias, 0.f));
    }
}

__global__ __launch_bounds__(256) void fuse2_k(const ushort* __restrict__ X1b,
                                               const int* __restrict__ sedge,
                                               const int* __restrict__ rstart,
                                               const ushort* __restrict__ WbT2,
                                               const float* __restrict__ b2,
                                               float* __restrict__ out) {
    __shared__ __align__(16) float Acc[NREL * TILE * ROWW];  // 69632 B
    __shared__ float InvL[NREL * TILE];                      // 1024 B
    __shared__ float P[4][TILE * NCLS];                      // 4096 B
    int tid = threadIdx.x;
    int dst0 = blockIdx.x * TILE;
    int wave = tid >> 6, lane = tid & 63;
    int mr = lane & 15, kq = lane >> 4;

    const ushort* xrow = X1b + (size_t)(dst0 + mr) * HID + kq * 8;
    bf16x8 ra0 = *(const bf16x8*)(xrow);
    bf16x8 ra1 = *(const bf16x8*)(xrow + 32);

    {
        int n = tid >> 4, r = tid & 15;
        int b = (dst0 + n) * NREL + r;
        int c0 = rstart[b], c1 = rstart[b + 1];
        InvL[r * TILE + n] = (c1 > c0) ? 1.0f / (float)(c1 - c0) : 0.0f;
    }
    {
        float* rowp = Acc + tid * ROWW;
        f32x4 z = {0.f, 0.f, 0.f, 0.f};
#pragma unroll
        for (int i = 0; i < 17; ++i) *(f32x4*)(rowp + i * 4) = z;
    }
    int lo = rstart[dst0 * NREL];
    int hi = rstart[(dst0 + TILE) * NREL];
    __syncthreads();

    unsigned accBase = (unsigned)(unsigned long long)(void*)Acc;
    gather_acc(accBase, X1b, sedge, lo, hi, tid);
    asm volatile("s_waitcnt lgkmcnt(0)" ::: "memory");
    __syncthreads();

    // MFMA: out = 16 cols; waves split tasks t = w, w+4, ...; wave 0 adds root
    const ushort* wb = WbT2 + mr * HID + kq * 8;
    f32x4 c = {0.f, 0.f, 0.f, 0.f};
    for (int t = wave; t < 16; t += 4) {
        bf16x8 bk0 = *(const bf16x8*)(wb + t * (NCLS * HID));
        bf16x8 bk1 = *(const bf16x8*)(wb + t * (NCLS * HID) + 32);
        LOAD_A(t)
        c = __builtin_amdgcn_mfma_f32_16x16x32_bf16(a0, bk0, c, 0, 0, 0);
        c = __builtin_amdgcn_mfma_f32_16x16x32_bf16(a1, bk1, c, 0, 0, 0);
    }
    if (wave == 0) {
        bf16x8 bk0 = *(const bf16x8*)(wb + 16 * (NCLS * HID));
        bf16x8 bk1 = *(const bf16x8*)(wb + 16 * (NCLS * HID) + 32);
        c = __builtin_amdgcn_mfma_f32_16x16x32_bf16(ra0, bk0, c, 0, 0, 0);
        c = __builtin_amdgcn_mfma_f32_16x16x32_bf16(ra1, bk1, c, 0, 0, 0);
    }
#pragma unroll
    for (int j = 0; j < 4; ++j) P[wave][(kq * 4 + j) * NCLS + mr] = c[j];
    __syncthreads();

    int row = tid >> 4, cc = tid & 15;
    float s = P[0][tid] + P[1][tid] + P[2][tid] + P[3][tid] + b2[cc];
    out[(size_t)(dst0 + row) * NCLS + cc] = s;
}

extern "C" void kernel_launch(void* const* d_in, const int* in_sizes, int n_in,
                              void* d_out, int out_size, void* d_ws, size_t ws_size,
                              hipStream_t stream) {
    const int* ei    = (const int*)d_in[0];
    const int* et    = (const int*)d_in[1];
    const float* x   = (const float*)d_in[2];
    const float* W1  = (const float*)d_in[3];
    const float* r1  = (const float*)d_in[4];
    const float* b1  = (const float*)d_in[5];
    const float* W2  = (const float*)d_in[6];
    const float* r2  = (const float*)d_in[7];
    const float* b2  = (const float*)d_in[8];
    float* out = (float*)d_out;

    int E = in_sizes[0] / 2;
    const int* srcp = ei;
    const int* dstp = ei + E;

    int*    bcnt  = (int*)d_ws;                 // doubles as rstart after scan3
    int*    rank  = bcnt + (NBKT + 20);
    int*    bsum  = rank + E;                   // 512 ints (NSB=391 used)
    int*    sedge = bsum + 512;
    ushort* WbT1  = (ushort*)(sedge + E);
    ushort* WbT2  = WbT1 + W1N;
    ushort* xb    = WbT2 + W2N;
    ushort* X1b   = xb + (size_t)N_NODES * HID;
    int*    rstart = bcnt;                      // alias (in-place scan)

    hipMemsetAsync(bcnt, 0, (NBKT + 20) * sizeof(int), stream);

    int eb = (E + 255) / 256;
    int cvtThreads = XCHUNKS + W1N + W2N;
    int cvtBlocks = (cvtThreads + 255) / 256;

    pre_k<<<eb + cvtBlocks, 256, 0, stream>>>(dstp, et, bcnt, rank, E,
                                              x, W1, r1, W2, r2, xb, WbT1, WbT2);
    scan1_k<<<NSB, 256, 0, stream>>>(bcnt, bsum);
    scan2_k<<<1, 512, 0, stream>>>(bsum, rstart, E);
    scan3_k<<<NSB, 256, 0, stream>>>(bcnt, bsum);
    scat_k<<<eb, 256, 0, stream>>>(srcp, dstp, et, rank, rstart, sedge, E);

    fuse1_k<<<NTB, 256, 0, stream>>>(xb, sedge, rstart, WbT1, b1, X1b);
    fuse2_k<<<NTB, 256, 0, stream>>>(X1b, sedge, rstart, WbT2, b2, out);
}

// Round 8
// 278.883 us; speedup vs baseline: 2.6532x; 2.6532x over previous
//
#include <hip/hip_runtime.h>
#include <hip/hip_bf16.h>

#define N_NODES 50000
#define NREL 16
#define HID 64
#define NCLS 16
#define NBKT (N_NODES * NREL)       // 800000 buckets (dst*16 + rel)
#define SB 2048                     // scan elems per block
#define NSB ((NBKT + SB - 1) / SB)  // 391
#define TILE 16                     // dst nodes per fused block (50000/16 exact)
#define NTB (N_NODES / TILE)        // 3125
#define XCHUNKS (N_NODES * HID / 8) // 400000
#define W1N (17 * HID * HID)        // 69632
#define W2N (17 * NCLS * HID)       // 17408

typedef __attribute__((ext_vector_type(8))) short bf16x8;
typedef __attribute__((ext_vector_type(4))) float f32x4;

static __device__ __forceinline__ unsigned short f2bf(float f) {
    __hip_bfloat16 h = __float2bfloat16(f);
    return *reinterpret_cast<unsigned short*>(&h);
}
static __device__ __forceinline__ float bf2f(unsigned short u) {
    __hip_bfloat16 h;
    *reinterpret_cast<unsigned short*>(&h) = u;
    return __bfloat162float(h);
}

// ---------------------------------------------------------------------------
// ws layout:
//   bcnt/rstart i32[800020] (zeroed; scan3 -> prefix IN PLACE)
//   | cursor i32[800000] (scan3 writes copy; scat consumes via atomicAdd)
//   | bsum i32[512] | sedge int2[E] {src | rel<<16, inv}
//   | WbT1 bf16[17*64*64] [t][n][k] | WbT2 bf16[17*16*64] [t][n][k]
//   | xb bf16[50000*64] | X1b bf16[50000*64]
// Fused layers, TILE=16: per tile, 32 groups = 16 nodes x 2 rel-halves
// (rels 0-7 / 8-15; runs never span groups -> race-free register
// accumulation). A-tile = 16 rel rows only (32 KB LDS -> 4 blocks/CU);
// root A-fragments come straight from global registers (round-4 trick).
// ---------------------------------------------------------------------------

// K0: merged count (bucket histogram) and cvt (x->bf16, transposed weights)
__global__ __launch_bounds__(256) void pre_k(const int* __restrict__ dstp,
                                             const int* __restrict__ et,
                                             int* __restrict__ bcnt, int E,
                                             const float* __restrict__ x,
                                             const float* __restrict__ W1,
                                             const float* __restrict__ root1,
                                             const float* __restrict__ W2,
                                             const float* __restrict__ root2,
                                             ushort* __restrict__ xb,
                                             ushort* __restrict__ WbT1,
                                             ushort* __restrict__ WbT2) {
    int eb = (E + 255) >> 8;
    if ((int)blockIdx.x < eb) {
        int i = blockIdx.x * 256 + threadIdx.x;
        if (i < E) atomicAdd(&bcnt[dstp[i] * NREL + et[i]], 1);
        return;
    }
    int i = (blockIdx.x - eb) * 256 + threadIdx.x;
    if (i < XCHUNKS) {
        float4 f0 = *(const float4*)(x + (size_t)i * 8);
        float4 f1 = *(const float4*)(x + (size_t)i * 8 + 4);
        bf16x8 o;
        o[0] = (short)f2bf(f0.x); o[1] = (short)f2bf(f0.y);
        o[2] = (short)f2bf(f0.z); o[3] = (short)f2bf(f0.w);
        o[4] = (short)f2bf(f1.x); o[5] = (short)f2bf(f1.y);
        o[6] = (short)f2bf(f1.z); o[7] = (short)f2bf(f1.w);
        *(bf16x8*)(xb + (size_t)i * 8) = o;
    } else {
        int j = i - XCHUNKS;
        if (j < W1N) {
            int t = j >> 12, rem = j & 4095, n = rem >> 6, k = rem & 63;
            float v = (t < 16) ? W1[(size_t)t * HID * HID + k * HID + n]
                               : root1[k * HID + n];
            WbT1[j] = f2bf(v);
        } else {
            int m = j - W1N;
            if (m < W2N) {
                int t = m >> 10, rem = m & 1023, n = rem >> 6, k = rem & 63;
                float v = (t < 16) ? W2[(size_t)t * HID * NCLS + k * NCLS + n]
                                   : root2[k * NCLS + n];
                WbT2[m] = f2bf(v);
            }
        }
    }
}

// K2a: per-block sums of bcnt (2048 elems / block, 8 per thread)
__global__ __launch_bounds__(256) void scan1_k(const int* __restrict__ bcnt,
                                               int* __restrict__ bsum) {
    int b = blockIdx.x, t = threadIdx.x;
    int base = b * SB + t * 8;
    int s = 0;
#pragma unroll
    for (int j = 0; j < 8; ++j)
        if (base + j < NBKT) s += bcnt[base + j];
#pragma unroll
    for (int off = 1; off < 64; off <<= 1) s += __shfl_xor(s, off, 64);
    __shared__ int ws[4];
    if ((t & 63) == 0) ws[t >> 6] = s;
    __syncthreads();
    if (t == 0) bsum[b] = ws[0] + ws[1] + ws[2] + ws[3];
}

// K2b: exclusive scan of bsum[NSB] (one 512-thread block); rstart[NBKT] = E
__global__ __launch_bounds__(512) void scan2_k(int* __restrict__ bsum,
                                               int* __restrict__ rstart, int E) {
    __shared__ int ts[512];
    int t = threadIdx.x;
    int v = (t < NSB) ? bsum[t] : 0;
    ts[t] = v;
    __syncthreads();
    int acc = v;
    for (int off = 1; off < 512; off <<= 1) {
        int u = (t >= off) ? ts[t - off] : 0;
        __syncthreads();
        acc += u;
        ts[t] = acc;
        __syncthreads();
    }
    if (t < NSB) bsum[t] = acc - v;
    if (t == 0) rstart[NBKT] = E;
}

// K2c: per-block exclusive scan IN PLACE (bcnt -> rstart) + cursor copy
__global__ __launch_bounds__(256) void scan3_k(int* __restrict__ bcnt,
                                               const int* __restrict__ bsum,
                                               int* __restrict__ cursor) {
    int b = blockIdx.x, t = threadIdx.x;
    int base = b * SB + t * 8;
    int a[8];
    int s = 0;
#pragma unroll
    for (int j = 0; j < 8; ++j) {
        a[j] = (base + j < NBKT) ? bcnt[base + j] : 0;
        s += a[j];
    }
    __shared__ int ts[256];
    ts[t] = s;
    __syncthreads();
    int acc = s;
    for (int off = 1; off < 256; off <<= 1) {
        int u = (t >= off) ? ts[t - off] : 0;
        __syncthreads();
        acc += u;
        ts[t] = acc;
        __syncthreads();
    }
    int run = bsum[b] + (acc - s);
#pragma unroll
    for (int j = 0; j < 8; ++j) {
        if (base + j < NBKT) {
            bcnt[base + j] = run;
            cursor[base + j] = run;
        }
        run += a[j];
    }
}

// K3: scatter; slot claimed via cursor atomic (rank pass eliminated).
// int2 {src | rel<<16, 1/cnt} — mean premultiplied.
__global__ __launch_bounds__(256) void scat_k(const int* __restrict__ srcp,
                                              const int* __restrict__ dstp,
                                              const int* __restrict__ et,
                                              const int* __restrict__ rstart,
                                              int* __restrict__ cursor,
                                              int2* __restrict__ sedge, int E) {
    int i = blockIdx.x * 256 + threadIdx.x;
    if (i < E) {
        int r = et[i];
        int b = dstp[i] * NREL + r;
        int p = atomicAdd(&cursor[b], 1);
        float inv = 1.0f / (float)(rstart[b + 1] - rstart[b]);
        sedge[p] = make_int2(srcp[i] | (r << 16), __float_as_int(inv));
    }
}

// ---------------------------------------------------------------------------
// Fused layer kernels. Ab = [16 rel][16 node][128 B] bf16, XOR-swizzled
// (byte ^= (node&7)<<4) on both write and read sides.
// ---------------------------------------------------------------------------

#define GFLUSH()                                                              \
    {                                                                         \
        bf16x8 o_;                                                            \
        o_[0] = (short)f2bf(acc[0]); o_[1] = (short)f2bf(acc[1]);             \
        o_[2] = (short)f2bf(acc[2]); o_[3] = (short)f2bf(acc[3]);             \
        o_[4] = (short)f2bf(acc[4]); o_[5] = (short)f2bf(acc[5]);             \
        o_[6] = (short)f2bf(acc[6]); o_[7] = (short)f2bf(acc[7]);             \
        *(bf16x8*)(Ab + ((curRel * (TILE * 128) + rowoff) ^ sw)) = o_;        \
        acc[0] = 0.f; acc[1] = 0.f; acc[2] = 0.f; acc[3] = 0.f;               \
        acc[4] = 0.f; acc[5] = 0.f; acc[6] = 0.f; acc[7] = 0.f;               \
    }

// Gather: 32 groups = 16 nodes x 2 rel-halves; each group scans its
// contiguous bucket range [rstart[n*16+h*8], rstart[n*16+h*8+8]).
// 16 clamped same-addr descriptor loads (broadcast), then 16 branchless
// feature loads as one cluster, then predicated consume.
static __device__ __forceinline__ void gather_tile(char* Ab,
                                                   const ushort* __restrict__ ft,
                                                   const int2* __restrict__ sedge,
                                                   const int* __restrict__ rstart,
                                                   int dst0, int tid) {
    int grp = tid >> 3, l8 = tid & 7;
    int g = grp & 15, h = grp >> 4;  // node row, rel half
    int node = dst0 + g;
    int b0 = node * NREL + h * 8;
    int lo = rstart[b0], hi = rstart[b0 + 8];
    int deg = hi - lo;
    int base = (deg > 0) ? lo : 0;
    int last = (deg > 0) ? hi - 1 : 0;

    int sw = (g & 7) << 4;
    int rowoff = (g << 7) + (l8 << 4);
    const bf16x8 zz = {0, 0, 0, 0, 0, 0, 0, 0};

    // 16 clamped descriptor loads (same addr across the 8 lanes -> broadcast)
    int2 d[16];
#pragma unroll
    for (int j = 0; j < 16; ++j) {
        int idx = base + j;
        if (idx > last) idx = last;
        d[j] = sedge[idx];
    }

    // zero this group's 8 relation rows (overlaps descriptor latency)
#pragma unroll
    for (int r = 0; r < 8; ++r)
        *(bf16x8*)(Ab + (((h * 8 + r) * (TILE * 128) + rowoff) ^ sw)) = zz;

    // 16 branchless feature loads (clamped descriptors are safe)
    const ushort* xcol = ft + l8 * 8;
    bf16x8 v[16];
#pragma unroll
    for (int j = 0; j < 16; ++j)
        v[j] = *(const bf16x8*)(xcol + (size_t)(d[j].x & 0xFFFF) * HID);
    __builtin_amdgcn_sched_barrier(0);

    float acc[8] = {0.f, 0.f, 0.f, 0.f, 0.f, 0.f, 0.f, 0.f};
    int curRel = h * 8;
#pragma unroll
    for (int j = 0; j < 16; ++j) {
        if (j < deg) {
            int r_ = (d[j].x >> 16) & 15;
            if (r_ != curRel) {
                GFLUSH();
                curRel = r_;
            }
            float inv_ = __int_as_float(d[j].y);
#pragma unroll
            for (int q = 0; q < 8; ++q)
                acc[q] = fmaf(inv_, bf2f((unsigned short)v[j][q]), acc[q]);
        }
    }
    // rare tail (deg > 16; Poisson(8) -> ~0.3% of groups)
    for (int e = lo + 16; e < hi; ++e) {
        int2 m = sedge[e];
        int r = (m.x >> 16) & 15;
        if (r != curRel) {
            GFLUSH();
            curRel = r;
        }
        float inv = __int_as_float(m.y);
        bf16x8 vv = *(const bf16x8*)(xcol + (size_t)(m.x & 0xFFFF) * HID);
#pragma unroll
        for (int q = 0; q < 8; ++q)
            acc[q] = fmaf(inv, bf2f((unsigned short)vv[q]), acc[q]);
    }
    if (deg > 0) GFLUSH();
}

__global__ __launch_bounds__(256, 3) void fuse1_k(const ushort* __restrict__ xb,
                                                  const int2* __restrict__ sedge,
                                                  const int* __restrict__ rstart,
                                                  const ushort* __restrict__ WbT1,
                                                  const float* __restrict__ b1,
                                                  ushort* __restrict__ X1b) {
    __shared__ bf16x8 Abuf[NREL * TILE * 8];  // 32768 B -> 4 blocks/CU
    char* Ab = (char*)Abuf;
    int tid = threadIdx.x;
    int dst0 = blockIdx.x * TILE;
    int wave = tid >> 6, lane = tid & 63;
    int mr = lane & 15, kq = lane >> 4;

    // root A-fragments straight from global (issued early, no LDS)
    const ushort* xrow = xb + (size_t)(dst0 + mr) * HID + kq * 8;
    bf16x8 ra0 = *(const bf16x8*)(xrow);
    bf16x8 ra1 = *(const bf16x8*)(xrow + 32);

    gather_tile(Ab, xb, sedge, rstart, dst0, tid);

    // MFMA: wave w owns out cols [w*16, w*16+16); A = 16 nodes x 64
    const ushort* wb = WbT1 + (wave * 16 + mr) * HID + kq * 8;
    int sw = (mr & 7) << 4;
    int a0o = ((mr << 7) + (kq << 4)) ^ sw;
    int a1o = ((mr << 7) + 64 + (kq << 4)) ^ sw;

    bf16x8 bk0 = *(const bf16x8*)(wb);
    bf16x8 bk1 = *(const bf16x8*)(wb + 32);
    __syncthreads();

    f32x4 c = {0.f, 0.f, 0.f, 0.f};
    for (int t = 0; t < 16; ++t) {
        bf16x8 nb0 = *(const bf16x8*)(wb + (t + 1) * 4096);
        bf16x8 nb1 = *(const bf16x8*)(wb + (t + 1) * 4096 + 32);
        const char* At = Ab + t * (TILE * 128);
        bf16x8 a0 = *(const bf16x8*)(At + a0o);
        bf16x8 a1 = *(const bf16x8*)(At + a1o);
        c = __builtin_amdgcn_mfma_f32_16x16x32_bf16(a0, bk0, c, 0, 0, 0);
        c = __builtin_amdgcn_mfma_f32_16x16x32_bf16(a1, bk1, c, 0, 0, 0);
        bk0 = nb0;
        bk1 = nb1;
    }
    // root (bk now holds task-16 fragments)
    c = __builtin_amdgcn_mfma_f32_16x16x32_bf16(ra0, bk0, c, 0, 0, 0);
    c = __builtin_amdgcn_mfma_f32_16x16x32_bf16(ra1, bk1, c, 0, 0, 0);

    float bias = b1[wave * 16 + mr];
    int col = wave * 16 + mr;
#pragma unroll
    for (int j = 0; j < 4; ++j) {
        int node = dst0 + kq * 4 + j;  // D row = quad*4+reg
        X1b[(size_t)node * HID + col] = f2bf(fmaxf(c[j] + bias, 0.f));
    }
}

__global__ __launch_bounds__(256, 3) void fuse2_k(const ushort* __restrict__ X1b,
                                                  const int2* __restrict__ sedge,
                                                  const int* __restrict__ rstart,
                                                  const ushort* __restrict__ WbT2,
                                                  const float* __restrict__ b2,
                                                  float* __restrict__ out) {
    __shared__ bf16x8 Abuf[NREL * TILE * 8];  // 32768 B
    __shared__ float P[4][TILE * NCLS];       // 4096 B
    char* Ab = (char*)Abuf;
    int tid = threadIdx.x;
    int dst0 = blockIdx.x * TILE;
    int wave = tid >> 6, lane = tid & 63;
    int mr = lane & 15, kq = lane >> 4;

    const ushort* xrow = X1b + (size_t)(dst0 + mr) * HID + kq * 8;
    bf16x8 ra0 = *(const bf16x8*)(xrow);
    bf16x8 ra1 = *(const bf16x8*)(xrow + 32);

    gather_tile(Ab, X1b, sedge, rstart, dst0, tid);
    __syncthreads();

    // MFMA: out = 16 cols; waves split tasks t = w, w+4, ...; wave 0 adds root
    const ushort* wb = WbT2 + mr * HID + kq * 8;
    int sw = (mr & 7) << 4;
    int a0o = ((mr << 7) + (kq << 4)) ^ sw;
    int a1o = ((mr << 7) + 64 + (kq << 4)) ^ sw;

    f32x4 c = {0.f, 0.f, 0.f, 0.f};
    for (int t = wave; t < 16; t += 4) {
        bf16x8 bk0 = *(const bf16x8*)(wb + t * (NCLS * HID));
        bf16x8 bk1 = *(const bf16x8*)(wb + t * (NCLS * HID) + 32);
        const char* At = Ab + t * (TILE * 128);
        bf16x8 a0 = *(const bf16x8*)(At + a0o);
        bf16x8 a1 = *(const bf16x8*)(At + a1o);
        c = __builtin_amdgcn_mfma_f32_16x16x32_bf16(a0, bk0, c, 0, 0, 0);
        c = __builtin_amdgcn_mfma_f32_16x16x32_bf16(a1, bk1, c, 0, 0, 0);
    }
    if (wave == 0) {
        bf16x8 bk0 = *(const bf16x8*)(wb + 16 * (NCLS * HID));
        bf16x8 bk1 = *(const bf16x8*)(wb + 16 * (NCLS * HID) + 32);
        c = __builtin_amdgcn_mfma_f32_16x16x32_bf16(ra0, bk0, c, 0, 0, 0);
        c = __builtin_amdgcn_mfma_f32_16x16x32_bf16(ra1, bk1, c, 0, 0, 0);
    }
#pragma unroll
    for (int j = 0; j < 4; ++j) P[wave][(kq * 4 + j) * NCLS + mr] = c[j];
    __syncthreads();

    int row = tid >> 4, cc = tid & 15;
    float s = P[0][tid] + P[1][tid] + P[2][tid] + P[3][tid] + b2[cc];
    out[(size_t)(dst0 + row) * NCLS + cc] = s;
}

extern "C" void kernel_launch(void* const* d_in, const int* in_sizes, int n_in,
                              void* d_out, int out_size, void* d_ws, size_t ws_size,
                              hipStream_t stream) {
    const int* ei    = (const int*)d_in[0];
    const int* et    = (const int*)d_in[1];
    const float* x   = (const float*)d_in[2];
    const float* W1  = (const float*)d_in[3];
    const float* r1  = (const float*)d_in[4];
    const float* b1  = (const float*)d_in[5];
    const float* W2  = (const float*)d_in[6];
    const float* r2  = (const float*)d_in[7];
    const float* b2  = (const float*)d_in[8];
    float* out = (float*)d_out;

    int E = in_sizes[0] / 2;
    const int* srcp = ei;
    const int* dstp = ei + E;

    int*    bcnt   = (int*)d_ws;                // doubles as rstart after scan3
    int*    cursor = bcnt + (NBKT + 20);
    int*    bsum   = cursor + NBKT;             // 512 ints (NSB=391 used)
    int2*   sedge  = (int2*)(bsum + 512);
    ushort* WbT1   = (ushort*)(sedge + E);
    ushort* WbT2   = WbT1 + W1N;
    ushort* xb     = WbT2 + W2N;
    ushort* X1b    = xb + (size_t)N_NODES * HID;
    int*    rstart = bcnt;                      // alias (in-place scan)

    hipMemsetAsync(bcnt, 0, (NBKT + 20) * sizeof(int), stream);

    int eb = (E + 255) / 256;
    int cvtThreads = XCHUNKS + W1N + W2N;
    int cvtBlocks = (cvtThreads + 255) / 256;

    pre_k<<<eb + cvtBlocks, 256, 0, stream>>>(dstp, et, bcnt, E,
                                              x, W1, r1, W2, r2, xb, WbT1, WbT2);
    scan1_k<<<NSB, 256, 0, stream>>>(bcnt, bsum);
    scan2_k<<<1, 512, 0, stream>>>(bsum, rstart, E);
    scan3_k<<<NSB, 256, 0, stream>>>(bcnt, bsum, cursor);
    scat_k<<<eb, 256, 0, stream>>>(srcp, dstp, et, rstart, cursor, sedge, E);

    fuse1_k<<<NTB, 256, 0, stream>>>(xb, sedge, rstart, WbT1, b1, X1b);
    fuse2_k<<<NTB, 256, 0, stream>>>(X1b, sedge, rstart, WbT2, b2, out);
}

// Round 9
// 264.583 us; speedup vs baseline: 2.7966x; 1.0540x over previous
//
#include <hip/hip_runtime.h>
#include <hip/hip_bf16.h>

#define N_NODES 50000
#define NREL 16
#define HID 64
#define NCLS 16
#define NBKT (N_NODES * NREL)       // 800000 buckets (dst*16 + rel)
#define SB 2048                     // scan elems per block
#define NSB ((NBKT + SB - 1) / SB)  // 391
#define TILE 32                     // dst nodes per fused block
#define NTB ((N_NODES + TILE - 1) / TILE)  // 1563
#define XCHUNKS (N_NODES * HID / 8)        // 400000
#define W1N (17 * HID * HID)               // 69632
#define W2N (17 * NCLS * HID)              // 17408

typedef __attribute__((ext_vector_type(8))) short bf16x8;
typedef __attribute__((ext_vector_type(4))) float f32x4;

static __device__ __forceinline__ unsigned short f2bf(float f) {
    __hip_bfloat16 h = __float2bfloat16(f);
    return *reinterpret_cast<unsigned short*>(&h);
}
static __device__ __forceinline__ float bf2f(unsigned short u) {
    __hip_bfloat16 h;
    *reinterpret_cast<unsigned short*>(&h) = u;
    return __bfloat162float(h);
}

// ---------------------------------------------------------------------------
// ws layout (R6 pre-pipeline, proven):
//   bcnt/rstart i32[800020] | rank i32[E] | bsum i32[512]
//   | sedge int2[E] {src | rel<<16, inv} | WbT1 | WbT2 | xb | X1b
// Fused layers: TILE=32, 512 threads. Gather = 64 groups (32 nodes x 2
// rel-halves, race-free). MFMA = 8 waves (4 col-groups x 2 m-halves) --
// keeps TILE=32 weight amortization while halving per-wave t-loop cost.
// Root row lives in registers; Ab = 16 rel rows = 64 KB -> 2 blocks/CU
// = 16 waves/CU during gather (2x R5).
// ---------------------------------------------------------------------------

// K0: merged rank (bucket count + per-edge rank) and cvt
__global__ __launch_bounds__(256) void pre_k(const int* __restrict__ dstp,
                                             const int* __restrict__ et,
                                             int* __restrict__ bcnt,
                                             int* __restrict__ rank, int E,
                                             const float* __restrict__ x,
                                             const float* __restrict__ W1,
                                             const float* __restrict__ root1,
                                             const float* __restrict__ W2,
                                             const float* __restrict__ root2,
                                             ushort* __restrict__ xb,
                                             ushort* __restrict__ WbT1,
                                             ushort* __restrict__ WbT2) {
    int eb = (E + 255) >> 8;
    if ((int)blockIdx.x < eb) {
        int i = blockIdx.x * 256 + threadIdx.x;
        if (i < E) {
            int b = dstp[i] * NREL + et[i];
            rank[i] = atomicAdd(&bcnt[b], 1);
        }
        return;
    }
    int i = (blockIdx.x - eb) * 256 + threadIdx.x;
    if (i < XCHUNKS) {
        float4 f0 = *(const float4*)(x + (size_t)i * 8);
        float4 f1 = *(const float4*)(x + (size_t)i * 8 + 4);
        bf16x8 o;
        o[0] = (short)f2bf(f0.x); o[1] = (short)f2bf(f0.y);
        o[2] = (short)f2bf(f0.z); o[3] = (short)f2bf(f0.w);
        o[4] = (short)f2bf(f1.x); o[5] = (short)f2bf(f1.y);
        o[6] = (short)f2bf(f1.z); o[7] = (short)f2bf(f1.w);
        *(bf16x8*)(xb + (size_t)i * 8) = o;
    } else {
        int j = i - XCHUNKS;
        if (j < W1N) {
            int t = j >> 12, rem = j & 4095, n = rem >> 6, k = rem & 63;
            float v = (t < 16) ? W1[(size_t)t * HID * HID + k * HID + n]
                               : root1[k * HID + n];
            WbT1[j] = f2bf(v);
        } else {
            int m = j - W1N;
            if (m < W2N) {
                int t = m >> 10, rem = m & 1023, n = rem >> 6, k = rem & 63;
                float v = (t < 16) ? W2[(size_t)t * HID * NCLS + k * NCLS + n]
                                   : root2[k * NCLS + n];
                WbT2[m] = f2bf(v);
            }
        }
    }
}

__global__ __launch_bounds__(256) void scan1_k(const int* __restrict__ bcnt,
                                               int* __restrict__ bsum) {
    int b = blockIdx.x, t = threadIdx.x;
    int base = b * SB + t * 8;
    int s = 0;
#pragma unroll
    for (int j = 0; j < 8; ++j)
        if (base + j < NBKT) s += bcnt[base + j];
#pragma unroll
    for (int off = 1; off < 64; off <<= 1) s += __shfl_xor(s, off, 64);
    __shared__ int ws[4];
    if ((t & 63) == 0) ws[t >> 6] = s;
    __syncthreads();
    if (t == 0) bsum[b] = ws[0] + ws[1] + ws[2] + ws[3];
}

__global__ __launch_bounds__(512) void scan2_k(int* __restrict__ bsum,
                                               int* __restrict__ rstart, int E) {
    __shared__ int ts[512];
    int t = threadIdx.x;
    int v = (t < NSB) ? bsum[t] : 0;
    ts[t] = v;
    __syncthreads();
    int acc = v;
    for (int off = 1; off < 512; off <<= 1) {
        int u = (t >= off) ? ts[t - off] : 0;
        __syncthreads();
        acc += u;
        ts[t] = acc;
        __syncthreads();
    }
    if (t < NSB) bsum[t] = acc - v;
    if (t == 0) rstart[NBKT] = E;
}

__global__ __launch_bounds__(256) void scan3_k(int* __restrict__ bcnt,
                                               const int* __restrict__ bsum) {
    int b = blockIdx.x, t = threadIdx.x;
    int base = b * SB + t * 8;
    int a[8];
    int s = 0;
#pragma unroll
    for (int j = 0; j < 8; ++j) {
        a[j] = (base + j < NBKT) ? bcnt[base + j] : 0;
        s += a[j];
    }
    __shared__ int ts[256];
    ts[t] = s;
    __syncthreads();
    int acc = s;
    for (int off = 1; off < 256; off <<= 1) {
        int u = (t >= off) ? ts[t - off] : 0;
        __syncthreads();
        acc += u;
        ts[t] = acc;
        __syncthreads();
    }
    int run = bsum[b] + (acc - s);
#pragma unroll
    for (int j = 0; j < 8; ++j) {
        if (base + j < NBKT) bcnt[base + j] = run;
        run += a[j];
    }
}

// K3: atomic-free scatter; int2 {src | rel<<16, 1/cnt}
__global__ __launch_bounds__(256) void scat_k(const int* __restrict__ srcp,
                                              const int* __restrict__ dstp,
                                              const int* __restrict__ et,
                                              const int* __restrict__ rank,
                                              const int* __restrict__ rstart,
                                              int2* __restrict__ sedge, int E) {
    int i = blockIdx.x * 256 + threadIdx.x;
    if (i < E) {
        int r = et[i];
        int b = dstp[i] * NREL + r;
        int lo = rstart[b], hi = rstart[b + 1];
        float inv = 1.0f / (float)(hi - lo);
        sedge[lo + rank[i]] = make_int2(srcp[i] | (r << 16), __float_as_int(inv));
    }
}

// ---------------------------------------------------------------------------
// Fused layers. Ab = [16 rel][32 node][128 B] bf16, XOR-swizzled
// (byte ^= (node&7)<<4) on write and read.
// ---------------------------------------------------------------------------

#define GFLUSH()                                                              \
    {                                                                         \
        bf16x8 o_;                                                            \
        o_[0] = (short)f2bf(acc[0]); o_[1] = (short)f2bf(acc[1]);             \
        o_[2] = (short)f2bf(acc[2]); o_[3] = (short)f2bf(acc[3]);             \
        o_[4] = (short)f2bf(acc[4]); o_[5] = (short)f2bf(acc[5]);             \
        o_[6] = (short)f2bf(acc[6]); o_[7] = (short)f2bf(acc[7]);             \
        *(bf16x8*)(Ab + ((curRel * (TILE * 128) + rowoff) ^ sw)) = o_;        \
        acc[0] = 0.f; acc[1] = 0.f; acc[2] = 0.f; acc[3] = 0.f;               \
        acc[4] = 0.f; acc[5] = 0.f; acc[6] = 0.f; acc[7] = 0.f;               \
    }

// Gather, 512 threads: 64 groups = 32 nodes x 2 rel-halves. Each group
// scans [rstart[n*16+h*8], rstart[n*16+h*8+8]) — rel runs never span
// groups, so LDS row writes are race-free. 16 clamped same-addr
// descriptor loads (broadcast), 16 branchless feature loads, consume.
static __device__ __forceinline__ void gather_tile(char* Ab,
                                                   const ushort* __restrict__ ft,
                                                   const int2* __restrict__ sedge,
                                                   const int* __restrict__ rstart,
                                                   int dst0, int tid) {
    int grp = tid >> 3, l8 = tid & 7;
    int g = grp & 31, h = grp >> 5;  // node row, rel half
    int node = dst0 + g;
    bool valid = node < N_NODES;
    int lo = 0, hi = 0;
    if (valid) {
        int b0 = node * NREL + h * 8;
        lo = rstart[b0];
        hi = rstart[b0 + 8];
    }
    int deg = hi - lo;
    int base = (deg > 0) ? lo : 0;
    int last = (deg > 0) ? hi - 1 : 0;

    int sw = (g & 7) << 4;
    int rowoff = (g << 7) + (l8 << 4);
    const bf16x8 zz = {0, 0, 0, 0, 0, 0, 0, 0};

    // 16 clamped descriptor loads (same addr across the 8 lanes)
    int2 d[16];
#pragma unroll
    for (int j = 0; j < 16; ++j) {
        int idx = base + j;
        if (idx > last) idx = last;
        d[j] = sedge[idx];
    }

    // zero this group's 8 relation rows (overlaps descriptor latency)
#pragma unroll
    for (int r = 0; r < 8; ++r)
        *(bf16x8*)(Ab + (((h * 8 + r) * (TILE * 128) + rowoff) ^ sw)) = zz;

    // 16 branchless feature loads
    const ushort* xcol = ft + l8 * 8;
    bf16x8 v[16];
#pragma unroll
    for (int j = 0; j < 16; ++j)
        v[j] = *(const bf16x8*)(xcol + (size_t)(d[j].x & 0xFFFF) * HID);
    __builtin_amdgcn_sched_barrier(0);

    float acc[8] = {0.f, 0.f, 0.f, 0.f, 0.f, 0.f, 0.f, 0.f};
    int curRel = h * 8;
#pragma unroll
    for (int j = 0; j < 16; ++j) {
        if (j < deg) {
            int r_ = (d[j].x >> 16) & 15;
            if (r_ != curRel) {
                GFLUSH();
                curRel = r_;
            }
            float inv_ = __int_as_float(d[j].y);
#pragma unroll
            for (int q = 0; q < 8; ++q)
                acc[q] = fmaf(inv_, bf2f((unsigned short)v[j][q]), acc[q]);
        }
    }
    // rare tail (deg > 16; Poisson(8))
    for (int e = lo + 16; e < hi; ++e) {
        int2 m = sedge[e];
        int r = (m.x >> 16) & 15;
        if (r != curRel) {
            GFLUSH();
            curRel = r;
        }
        float inv = __int_as_float(m.y);
        bf16x8 vv = *(const bf16x8*)(xcol + (size_t)(m.x & 0xFFFF) * HID);
#pragma unroll
        for (int q = 0; q < 8; ++q)
            acc[q] = fmaf(inv, bf2f((unsigned short)vv[q]), acc[q]);
    }
    if (deg > 0) GFLUSH();
}

__global__ __launch_bounds__(512, 4) void fuse1_k(const ushort* __restrict__ xb,
                                                  const int2* __restrict__ sedge,
                                                  const int* __restrict__ rstart,
                                                  const ushort* __restrict__ WbT1,
                                                  const float* __restrict__ b1,
                                                  ushort* __restrict__ X1b) {
    __shared__ bf16x8 Abuf[NREL * TILE * 8];  // 65536 B -> 2 blocks/CU, 16 waves
    char* Ab = (char*)Abuf;
    int tid = threadIdx.x;
    int dst0 = blockIdx.x * TILE;
    int wave = tid >> 6, lane = tid & 63;
    int mr = lane & 15, kq = lane >> 4;
    int cg = wave & 3, mh = wave >> 2;  // col-group, m-half

    // root A-frags for this wave's m-half (registers; clamped row)
    int rnode = dst0 + mh * 16 + mr;
    if (rnode >= N_NODES) rnode = N_NODES - 1;
    const ushort* xrow = xb + (size_t)rnode * HID + kq * 8;
    bf16x8 ra0 = *(const bf16x8*)(xrow);
    bf16x8 ra1 = *(const bf16x8*)(xrow + 32);

    gather_tile(Ab, xb, sedge, rstart, dst0, tid);

    // MFMA: wave (cg, mh) computes D[mh*16..+15][cg*16..+15]
    const ushort* wb = WbT1 + (cg * 16 + mr) * HID + kq * 8;
    int sw = (mr & 7) << 4;
    int arow = mh * 16 + mr;
    int a0o = ((arow << 7) + (kq << 4)) ^ sw;
    int a1o = ((arow << 7) + 64 + (kq << 4)) ^ sw;

    bf16x8 bk0 = *(const bf16x8*)(wb);
    bf16x8 bk1 = *(const bf16x8*)(wb + 32);
    __syncthreads();

    f32x4 c = {0.f, 0.f, 0.f, 0.f};
    for (int t = 0; t < 16; ++t) {
        bf16x8 nb0 = *(const bf16x8*)(wb + (t + 1) * 4096);
        bf16x8 nb1 = *(const bf16x8*)(wb + (t + 1) * 4096 + 32);
        const char* At = Ab + t * (TILE * 128);
        bf16x8 a0 = *(const bf16x8*)(At + a0o);
        bf16x8 a1 = *(const bf16x8*)(At + a1o);
        c = __builtin_amdgcn_mfma_f32_16x16x32_bf16(a0, bk0, c, 0, 0, 0);
        c = __builtin_amdgcn_mfma_f32_16x16x32_bf16(a1, bk1, c, 0, 0, 0);
        bk0 = nb0;
        bk1 = nb1;
    }
    // root (bk holds slice 16)
    c = __builtin_amdgcn_mfma_f32_16x16x32_bf16(ra0, bk0, c, 0, 0, 0);
    c = __builtin_amdgcn_mfma_f32_16x16x32_bf16(ra1, bk1, c, 0, 0, 0);

    float bias = b1[cg * 16 + mr];
    int col = cg * 16 + mr;
#pragma unroll
    for (int j = 0; j < 4; ++j) {
        int node = dst0 + mh * 16 + kq * 4 + j;  // D row = quad*4+reg
        if (node < N_NODES)
            X1b[(size_t)node * HID + col] = f2bf(fmaxf(c[j] + bias, 0.f));
    }
}

__global__ __launch_bounds__(512, 4) void fuse2_k(const ushort* __restrict__ X1b,
                                                  const int2* __restrict__ sedge,
                                                  const int* __restrict__ rstart,
                                                  const ushort* __restrict__ WbT2,
                                                  const float* __restrict__ b2,
                                                  float* __restrict__ out) {
    __shared__ bf16x8 Abuf[NREL * TILE * 8];  // 65536 B
    __shared__ float P[4][TILE * NCLS];       // 8192 B
    char* Ab = (char*)Abuf;
    int tid = threadIdx.x;
    int dst0 = blockIdx.x * TILE;
    int wave = tid >> 6, lane = tid & 63;
    int mr = lane & 15, kq = lane >> 4;

    // root A-frags (wave 0 only consumes; loads predicated, clamped rows)
    bf16x8 ra00, ra01, ra10, ra11;
    if (wave == 0) {
        int r0 = dst0 + mr;
        if (r0 >= N_NODES) r0 = N_NODES - 1;
        int r1 = dst0 + 16 + mr;
        if (r1 >= N_NODES) r1 = N_NODES - 1;
        const ushort* x0 = X1b + (size_t)r0 * HID + kq * 8;
        const ushort* x1 = X1b + (size_t)r1 * HID + kq * 8;
        ra00 = *(const bf16x8*)(x0);
        ra01 = *(const bf16x8*)(x0 + 32);
        ra10 = *(const bf16x8*)(x1);
        ra11 = *(const bf16x8*)(x1 + 32);
    }

    gather_tile(Ab, X1b, sedge, rstart, dst0, tid);
    __syncthreads();

    // MFMA: 8 waves split 16 tasks (t = w, w+8); wave 0 adds root (t=16)
    const ushort* wb = WbT2 + mr * HID + kq * 8;
    int sw = (mr & 7) << 4;
    int a00o = ((mr << 7) + (kq << 4)) ^ sw;
    int a01o = ((mr << 7) + 64 + (kq << 4)) ^ sw;
    int a10o = (((16 + mr) << 7) + (kq << 4)) ^ sw;
    int a11o = (((16 + mr) << 7) + 64 + (kq << 4)) ^ sw;

    f32x4 c0 = {0.f, 0.f, 0.f, 0.f}, c1 = {0.f, 0.f, 0.f, 0.f};
    for (int t = wave; t < 16; t += 8) {
        bf16x8 bk0 = *(const bf16x8*)(wb + t * 1024);
        bf16x8 bk1 = *(const bf16x8*)(wb + t * 1024 + 32);
        const char* At = Ab + t * (TILE * 128);
        bf16x8 a00 = *(const bf16x8*)(At + a00o);
        bf16x8 a01 = *(const bf16x8*)(At + a01o);
        bf16x8 a10 = *(const bf16x8*)(At + a10o);
        bf16x8 a11 = *(const bf16x8*)(At + a11o);
        c0 = __builtin_amdgcn_mfma_f32_16x16x32_bf16(a00, bk0, c0, 0, 0, 0);
        c0 = __builtin_amdgcn_mfma_f32_16x16x32_bf16(a01, bk1, c0, 0, 0, 0);
        c1 = __builtin_amdgcn_mfma_f32_16x16x32_bf16(a10, bk0, c1, 0, 0, 0);
        c1 = __builtin_amdgcn_mfma_f32_16x16x32_bf16(a11, bk1, c1, 0, 0, 0);
    }
    if (wave == 0) {
        bf16x8 bk0 = *(const bf16x8*)(wb + 16 * 1024);
        bf16x8 bk1 = *(const bf16x8*)(wb + 16 * 1024 + 32);
        c0 = __builtin_amdgcn_mfma_f32_16x16x32_bf16(ra00, bk0, c0, 0, 0, 0);
        c0 = __builtin_amdgcn_mfma_f32_16x16x32_bf16(ra01, bk1, c0, 0, 0, 0);
        c1 = __builtin_amdgcn_mfma_f32_16x16x32_bf16(ra10, bk0, c1, 0, 0, 0);
        c1 = __builtin_amdgcn_mfma_f32_16x16x32_bf16(ra11, bk1, c1, 0, 0, 0);
    }

    // two-phase partial accumulation: waves 0-3 write, waves 4-7 add
    if (wave < 4) {
#pragma unroll
        for (int j = 0; j < 4; ++j) {
            P[wave][(kq * 4 + j) * NCLS + mr] = c0[j];
            P[wave][(16 + kq * 4 + j) * NCLS + mr] = c1[j];
        }
    }
    __syncthreads();
    if (wave >= 4) {
#pragma unroll
        for (int j = 0; j < 4; ++j) {
            P[wave - 4][(kq * 4 + j) * NCLS + mr] += c0[j];
            P[wave - 4][(16 + kq * 4 + j) * NCLS + mr] += c1[j];
        }
    }
    __syncthreads();

    // reduce + bias: 512 threads x 1 f32
    int row = tid >> 4, cc = tid & 15;
    float s = P[0][tid] + P[1][tid] + P[2][tid] + P[3][tid] + b2[cc];
    if (dst0 + row < N_NODES) out[(size_t)(dst0 + row) * NCLS + cc] = s;
}

extern "C" void kernel_launch(void* const* d_in, const int* in_sizes, int n_in,
                              void* d_out, int out_size, void* d_ws, size_t ws_size,
                              hipStream_t stream) {
    const int* ei    = (const int*)d_in[0];
    const int* et    = (const int*)d_in[1];
    const float* x   = (const float*)d_in[2];
    const float* W1  = (const float*)d_in[3];
    const float* r1  = (const float*)d_in[4];
    const float* b1  = (const float*)d_in[5];
    const float* W2  = (const float*)d_in[6];
    const float* r2  = (const float*)d_in[7];
    const float* b2  = (const float*)d_in[8];
    float* out = (float*)d_out;

    int E = in_sizes[0] / 2;
    const int* srcp = ei;
    const int* dstp = ei + E;

    int*    bcnt  = (int*)d_ws;                 // doubles as rstart after scan3
    int*    rank  = bcnt + (NBKT + 20);
    int*    bsum  = rank + E;                   // 512 ints (NSB=391 used)
    int2*   sedge = (int2*)(bsum + 512);
    ushort* WbT1  = (ushort*)(sedge + E);
    ushort* WbT2  = WbT1 + W1N;
    ushort* xb    = WbT2 + W2N;
    ushort* X1b   = xb + (size_t)N_NODES * HID;
    int*    rstart = bcnt;                      // alias (in-place scan)

    hipMemsetAsync(bcnt, 0, (NBKT + 20) * sizeof(int), stream);

    int eb = (E + 255) / 256;
    int cvtThreads = XCHUNKS + W1N + W2N;
    int cvtBlocks = (cvtThreads + 255) / 256;

    pre_k<<<eb + cvtBlocks, 256, 0, stream>>>(dstp, et, bcnt, rank, E,
                                              x, W1, r1, W2, r2, xb, WbT1, WbT2);
    scan1_k<<<NSB, 256, 0, stream>>>(bcnt, bsum);
    scan2_k<<<1, 512, 0, stream>>>(bsum, rstart, E);
    scan3_k<<<NSB, 256, 0, stream>>>(bcnt, bsum);
    scat_k<<<eb, 256, 0, stream>>>(srcp, dstp, et, rank, rstart, sedge, E);

    fuse1_k<<<NTB, 512, 0, stream>>>(xb, sedge, rstart, WbT1, b1, X1b);
    fuse2_k<<<NTB, 512, 0, stream>>>(X1b, sedge, rstart, WbT2, b2, out);
}

// Round 10
// 248.795 us; speedup vs baseline: 2.9741x; 1.0635x over previous
//
#include <hip/hip_runtime.h>
#include <hip/hip_bf16.h>

#define N_NODES 50000
#define NREL 16
#define HID 64
#define NCLS 16
#define NBKT (N_NODES * NREL)       // 800000 buckets (dst*16 + rel)
#define SB 2048                     // scan elems per block
#define NSB ((NBKT + SB - 1) / SB)  // 391
#define TILE 32                     // dst nodes per tile
#define NTB ((N_NODES + TILE - 1) / TILE)  // 1563
#define PGRID 256                   // persistent blocks (1/CU)
#define XCHUNKS (N_NODES * HID / 8)        // 400000
#define W1N (17 * HID * HID)               // 69632
#define W2N (17 * NCLS * HID)              // 17408

typedef __attribute__((ext_vector_type(8))) short bf16x8;
typedef __attribute__((ext_vector_type(4))) float f32x4;
typedef __attribute__((ext_vector_type(2))) int i32x2;

static __device__ __forceinline__ unsigned short f2bf(float f) {
    __hip_bfloat16 h = __float2bfloat16(f);
    return *reinterpret_cast<unsigned short*>(&h);
}
static __device__ __forceinline__ float bf2f(unsigned short u) {
    __hip_bfloat16 h;
    *reinterpret_cast<unsigned short*>(&h) = u;
    return __bfloat162float(h);
}

#define MFMA16(A, B, C) __builtin_amdgcn_mfma_f32_16x16x32_bf16((A), (B), (C), 0, 0, 0)

// Inline-asm loads: cannot be sunk/split by the compiler; results valid only
// after VWAIT0 (s_waitcnt vmcnt(0) + sched_barrier per rule #18).
#define LD128A(D, P) \
    asm volatile("global_load_dwordx4 %0, %1, off" : "=v"(D) : "v"((const void*)(P)) : "memory")
#define LD64A(D, P) \
    asm volatile("global_load_dwordx2 %0, %1, off" : "=v"(D) : "v"((const void*)(P)) : "memory")
#define VWAIT0()                                           \
    do {                                                   \
        asm volatile("s_waitcnt vmcnt(0)" ::: "memory");   \
        __builtin_amdgcn_sched_barrier(0);                 \
    } while (0)

// ---------------------------------------------------------------------------
// ws layout (R6 pre-pipeline, proven):
//   bcnt/rstart i32[800020] | rank i32[E] | bsum i32[512]
//   | sedge int2[E] {src | rel<<16, inv} | WbT1 | WbT2 | xb | X1b
// Fused layers: persistent 256 blocks x 512 threads, double-buffered A-tile
// (2 x 64KB LDS). Per tile: issue next-tile desc (asm) -> MFMA half1 ->
// wait+issue next-tile features (asm) -> MFMA half2 + epilogue -> wait ->
// consume into other buffer. Weights live in registers (preloaded once per
// block; tasks split across waves + LDS P-reduce) so the steady loop has
// no compiler-visible load results -> no injected vmcnt drains.
// ---------------------------------------------------------------------------

// K0: merged rank (bucket count + per-edge rank) and cvt
__global__ __launch_bounds__(256) void pre_k(const int* __restrict__ dstp,
                                             const int* __restrict__ et,
                                             int* __restrict__ bcnt,
                                             int* __restrict__ rank, int E,
                                             const float* __restrict__ x,
                                             const float* __restrict__ W1,
                                             const float* __restrict__ root1,
                                             const float* __restrict__ W2,
                                             const float* __restrict__ root2,
                                             ushort* __restrict__ xb,
                                             ushort* __restrict__ WbT1,
                                             ushort* __restrict__ WbT2) {
    int eb = (E + 255) >> 8;
    if ((int)blockIdx.x < eb) {
        int i = blockIdx.x * 256 + threadIdx.x;
        if (i < E) {
            int b = dstp[i] * NREL + et[i];
            rank[i] = atomicAdd(&bcnt[b], 1);
        }
        return;
    }
    int i = (blockIdx.x - eb) * 256 + threadIdx.x;
    if (i < XCHUNKS) {
        float4 f0 = *(const float4*)(x + (size_t)i * 8);
        float4 f1 = *(const float4*)(x + (size_t)i * 8 + 4);
        bf16x8 o;
        o[0] = (short)f2bf(f0.x); o[1] = (short)f2bf(f0.y);
        o[2] = (short)f2bf(f0.z); o[3] = (short)f2bf(f0.w);
        o[4] = (short)f2bf(f1.x); o[5] = (short)f2bf(f1.y);
        o[6] = (short)f2bf(f1.z); o[7] = (short)f2bf(f1.w);
        *(bf16x8*)(xb + (size_t)i * 8) = o;
    } else {
        int j = i - XCHUNKS;
        if (j < W1N) {
            int t = j >> 12, rem = j & 4095, n = rem >> 6, k = rem & 63;
            float v = (t < 16) ? W1[(size_t)t * HID * HID + k * HID + n]
                               : root1[k * HID + n];
            WbT1[j] = f2bf(v);
        } else {
            int m = j - W1N;
            if (m < W2N) {
                int t = m >> 10, rem = m & 1023, n = rem >> 6, k = rem & 63;
                float v = (t < 16) ? W2[(size_t)t * HID * NCLS + k * NCLS + n]
                                   : root2[k * NCLS + n];
                WbT2[m] = f2bf(v);
            }
        }
    }
}

__global__ __launch_bounds__(256) void scan1_k(const int* __restrict__ bcnt,
                                               int* __restrict__ bsum) {
    int b = blockIdx.x, t = threadIdx.x;
    int base = b * SB + t * 8;
    int s = 0;
#pragma unroll
    for (int j = 0; j < 8; ++j)
        if (base + j < NBKT) s += bcnt[base + j];
#pragma unroll
    for (int off = 1; off < 64; off <<= 1) s += __shfl_xor(s, off, 64);
    __shared__ int ws[4];
    if ((t & 63) == 0) ws[t >> 6] = s;
    __syncthreads();
    if (t == 0) bsum[b] = ws[0] + ws[1] + ws[2] + ws[3];
}

__global__ __launch_bounds__(512) void scan2_k(int* __restrict__ bsum,
                                               int* __restrict__ rstart, int E) {
    __shared__ int ts[512];
    int t = threadIdx.x;
    int v = (t < NSB) ? bsum[t] : 0;
    ts[t] = v;
    __syncthreads();
    int acc = v;
    for (int off = 1; off < 512; off <<= 1) {
        int u = (t >= off) ? ts[t - off] : 0;
        __syncthreads();
        acc += u;
        ts[t] = acc;
        __syncthreads();
    }
    if (t < NSB) bsum[t] = acc - v;
    if (t == 0) rstart[NBKT] = E;
}

__global__ __launch_bounds__(256) void scan3_k(int* __restrict__ bcnt,
                                               const int* __restrict__ bsum) {
    int b = blockIdx.x, t = threadIdx.x;
    int base = b * SB + t * 8;
    int a[8];
    int s = 0;
#pragma unroll
    for (int j = 0; j < 8; ++j) {
        a[j] = (base + j < NBKT) ? bcnt[base + j] : 0;
        s += a[j];
    }
    __shared__ int ts[256];
    ts[t] = s;
    __syncthreads();
    int acc = s;
    for (int off = 1; off < 256; off <<= 1) {
        int u = (t >= off) ? ts[t - off] : 0;
        __syncthreads();
        acc += u;
        ts[t] = acc;
        __syncthreads();
    }
    int run = bsum[b] + (acc - s);
#pragma unroll
    for (int j = 0; j < 8; ++j) {
        if (base + j < NBKT) bcnt[base + j] = run;
        run += a[j];
    }
}

// K3: atomic-free scatter; int2 {src | rel<<16, 1/cnt}
__global__ __launch_bounds__(256) void scat_k(const int* __restrict__ srcp,
                                              const int* __restrict__ dstp,
                                              const int* __restrict__ et,
                                              const int* __restrict__ rank,
                                              const int* __restrict__ rstart,
                                              int2* __restrict__ sedge, int E) {
    int i = blockIdx.x * 256 + threadIdx.x;
    if (i < E) {
        int r = et[i];
        int b = dstp[i] * NREL + r;
        int lo = rstart[b], hi = rstart[b + 1];
        float inv = 1.0f / (float)(hi - lo);
        sedge[lo + rank[i]] = make_int2(srcp[i] | (r << 16), __float_as_int(inv));
    }
}

// ---------------------------------------------------------------------------
// Gather building blocks (shared by fuse1/fuse2 via macros).
// 64 groups = 32 nodes x 2 rel-halves; rel runs never span groups.
// Ab row layout: [16 rel][32 node][128 B], XOR-swizzled byte^=((node&7)<<4).
// ---------------------------------------------------------------------------

#define RSTART_LOAD(T, LO, HI)                                                \
    do {                                                                      \
        int node_ = (T) * TILE + g;                                           \
        LO = 0; HI = 0;                                                       \
        if (node_ < N_NODES) {                                                \
            int b0_ = node_ * NREL + h * 8;                                   \
            LO = rstart[b0_];                                                 \
            HI = rstart[b0_ + 8];                                             \
        }                                                                     \
    } while (0)

#define DESC_ISSUE(LO, HI)                                                    \
    do {                                                                      \
        int dg_ = (HI) - (LO);                                                \
        int bs_ = dg_ > 0 ? (LO) : 0;                                         \
        int lt_ = dg_ > 0 ? (HI)-1 : 0;                                       \
        _Pragma("unroll") for (int j_ = 0; j_ < 16; ++j_) {                   \
            int ix_ = bs_ + j_;                                               \
            if (ix_ > lt_) ix_ = lt_;                                         \
            LD64A(d[j_], sedge + ix_);                                        \
        }                                                                     \
    } while (0)

#define FEAT_ISSUE()                                                          \
    do {                                                                      \
        _Pragma("unroll") for (int j_ = 0; j_ < 16; ++j_)                     \
            LD128A(v[j_], xcol + (size_t)(d[j_].x & 0xFFFF) * HID);           \
    } while (0)

#define GFLUSHX(ABP)                                                          \
    {                                                                         \
        bf16x8 o_;                                                            \
        o_[0] = (short)f2bf(acc_[0]); o_[1] = (short)f2bf(acc_[1]);           \
        o_[2] = (short)f2bf(acc_[2]); o_[3] = (short)f2bf(acc_[3]);           \
        o_[4] = (short)f2bf(acc_[4]); o_[5] = (short)f2bf(acc_[5]);           \
        o_[6] = (short)f2bf(acc_[6]); o_[7] = (short)f2bf(acc_[7]);           \
        *(bf16x8*)((ABP) + ((curRel_ * (TILE * 128) + rowoff) ^ swg)) = o_;   \
        acc_[0] = 0.f; acc_[1] = 0.f; acc_[2] = 0.f; acc_[3] = 0.f;           \
        acc_[4] = 0.f; acc_[5] = 0.f; acc_[6] = 0.f; acc_[7] = 0.f;           \
    }

#define CONSUME(ABP, LO, HI)                                                  \
    do {                                                                      \
        char* abp_ = (char*)(ABP);                                            \
        int deg_ = (HI) - (LO);                                               \
        const bf16x8 zz_ = {0, 0, 0, 0, 0, 0, 0, 0};                          \
        _Pragma("unroll") for (int r_ = 0; r_ < 8; ++r_)                      \
            *(bf16x8*)(abp_ + (((h * 8 + r_) * (TILE * 128) + rowoff) ^ swg)) = zz_; \
        float acc_[8] = {0.f, 0.f, 0.f, 0.f, 0.f, 0.f, 0.f, 0.f};             \
        int curRel_ = h * 8;                                                  \
        _Pragma("unroll") for (int j_ = 0; j_ < 16; ++j_) {                   \
            if (j_ < deg_) {                                                  \
                int rr_ = (d[j_].x >> 16) & 15;                               \
                if (rr_ != curRel_) { GFLUSHX(abp_); curRel_ = rr_; }         \
                float iv_ = __int_as_float(d[j_].y);                          \
                _Pragma("unroll") for (int q_ = 0; q_ < 8; ++q_)              \
                    acc_[q_] = fmaf(iv_, bf2f((unsigned short)v[j_][q_]), acc_[q_]); \
            }                                                                 \
        }                                                                     \
        for (int e_ = (LO) + 16; e_ < (HI); ++e_) { /* rare tail */           \
            int2 m_ = sedge[e_];                                              \
            int rr_ = (m_.x >> 16) & 15;                                      \
            if (rr_ != curRel_) { GFLUSHX(abp_); curRel_ = rr_; }             \
            float iv_ = __int_as_float(m_.y);                                 \
            bf16x8 vv_ = *(const bf16x8*)(xcol + (size_t)(m_.x & 0xFFFF) * HID); \
            _Pragma("unroll") for (int q_ = 0; q_ < 8; ++q_)                  \
                acc_[q_] = fmaf(iv_, bf2f((unsigned short)vv_[q_]), acc_[q_]); \
        }                                                                     \
        if (deg_ > 0) GFLUSHX(abp_);                                          \
    } while (0)

__global__ __launch_bounds__(512, 2) void fuse1_k(const ushort* __restrict__ xb,
                                                  const int2* __restrict__ sedge,
                                                  const int* __restrict__ rstart,
                                                  const ushort* __restrict__ WbT1,
                                                  const float* __restrict__ b1,
                                                  ushort* __restrict__ X1b) {
    __shared__ bf16x8 Abuf[2][NREL * TILE * 8];  // 131072 B
    __shared__ float P[4][TILE][16];             // 8192 B
    int tid = threadIdx.x, bid = blockIdx.x;
    int wave = tid >> 6, lane = tid & 63;
    int mr = lane & 15, kq = lane >> 4;
    int cg = wave & 3, th = wave >> 2;  // col-group, task-half
    int grp = tid >> 3, l8 = tid & 7;
    int g = grp & 31, h = grp >> 5;
    int swg = (g & 7) << 4;
    int rowoff = (g << 7) + (l8 << 4);
    const ushort* xcol = xb + l8 * 8;
    int sw = (mr & 7) << 4;
    int a00o = ((mr << 7) + (kq << 4)) ^ sw;
    int a01o = ((mr << 7) + 64 + (kq << 4)) ^ sw;
    int a10o = (((16 + mr) << 7) + (kq << 4)) ^ sw;
    int a11o = (((16 + mr) << 7) + 64 + (kq << 4)) ^ sw;

    // weights in registers: this wave's 8 tasks (th*8+i) + root (t=16)
    const ushort* wbase = WbT1 + (cg * 16 + mr) * HID + kq * 8;
    bf16x8 w0[8], w1[8];
#pragma unroll
    for (int i = 0; i < 8; ++i) {
        w0[i] = *(const bf16x8*)(wbase + (th * 8 + i) * 4096);
        w1[i] = *(const bf16x8*)(wbase + (th * 8 + i) * 4096 + 32);
    }
    bf16x8 wr0 = *(const bf16x8*)(wbase + 16 * 4096);
    bf16x8 wr1 = *(const bf16x8*)(wbase + 16 * 4096 + 32);
    float4 bv = *(const float4*)(b1 + ((tid * 4) & 63));

    i32x2 d[16];
    bf16x8 v[16];

    // prologue: gather tile `bid` into Abuf[0] (serial, once)
    int lo, hi;
    RSTART_LOAD(bid, lo, hi);
    DESC_ISSUE(lo, hi);
    VWAIT0();
    FEAT_ISSUE();
    VWAIT0();
    CONSUME(&Abuf[0][0], lo, hi);
    int cur = 0;

    for (int k = 0;; ++k) {
        int tile = bid + k * PGRID;
        int dst0 = tile * TILE;
        bool hasNext = (tile + PGRID) < NTB;
        int nlo = 0, nhi = 0;
        if (hasNext) RSTART_LOAD(tile + PGRID, nlo, nhi);
        __syncthreads();  // Abuf[cur] visible to all
        if (hasNext) DESC_ISSUE(nlo, nhi);
        // root A-frags for this tile (asm; clamped rows)
        int r0 = dst0 + mr;      if (r0 >= N_NODES) r0 = N_NODES - 1;
        int r1 = dst0 + 16 + mr; if (r1 >= N_NODES) r1 = N_NODES - 1;
        bf16x8 ra00, ra01, ra10, ra11;
        LD128A(ra00, xb + (size_t)r0 * HID + kq * 8);
        LD128A(ra01, xb + (size_t)r0 * HID + kq * 8 + 32);
        LD128A(ra10, xb + (size_t)r1 * HID + kq * 8);
        LD128A(ra11, xb + (size_t)r1 * HID + kq * 8 + 32);

        const char* Abase = (const char*)&Abuf[cur][0] + th * (8 * TILE * 128);
        f32x4 c0 = {0.f, 0.f, 0.f, 0.f}, c1 = {0.f, 0.f, 0.f, 0.f};
#pragma unroll
        for (int i = 0; i < 4; ++i) {  // first half: desc latency hides here
            const char* At = Abase + i * (TILE * 128);
            bf16x8 a00 = *(const bf16x8*)(At + a00o);
            bf16x8 a01 = *(const bf16x8*)(At + a01o);
            bf16x8 a10 = *(const bf16x8*)(At + a10o);
            bf16x8 a11 = *(const bf16x8*)(At + a11o);
            c0 = MFMA16(a00, w0[i], c0);
            c0 = MFMA16(a01, w1[i], c0);
            c1 = MFMA16(a10, w0[i], c1);
            c1 = MFMA16(a11, w1[i], c1);
        }
        VWAIT0();  // desc + root ready
        if (hasNext) FEAT_ISSUE();  // feature latency hides under half 2
#pragma unroll
        for (int i = 4; i < 8; ++i) {
            const char* At = Abase + i * (TILE * 128);
            bf16x8 a00 = *(const bf16x8*)(At + a00o);
            bf16x8 a01 = *(const bf16x8*)(At + a01o);
            bf16x8 a10 = *(const bf16x8*)(At + a10o);
            bf16x8 a11 = *(const bf16x8*)(At + a11o);
            c0 = MFMA16(a00, w0[i], c0);
            c0 = MFMA16(a01, w1[i], c0);
            c1 = MFMA16(a10, w0[i], c1);
            c1 = MFMA16(a11, w1[i], c1);
        }
        if (th) {  // root task
            c0 = MFMA16(ra00, wr0, c0);
            c0 = MFMA16(ra01, wr1, c0);
            c1 = MFMA16(ra10, wr0, c1);
            c1 = MFMA16(ra11, wr1, c1);
        }
        // cross-half reduce in LDS P
        if (th == 0) {
#pragma unroll
            for (int j = 0; j < 4; ++j) {
                P[cg][kq * 4 + j][mr] = c0[j];
                P[cg][16 + kq * 4 + j][mr] = c1[j];
            }
        }
        __syncthreads();
        if (th == 1) {
#pragma unroll
            for (int j = 0; j < 4; ++j) {
                P[cg][kq * 4 + j][mr] += c0[j];
                P[cg][16 + kq * 4 + j][mr] += c1[j];
            }
        }
        __syncthreads();
        {
            int idx = tid * 4, row = idx >> 6, colb = idx & 63;
            int node = dst0 + row;
            if (node < N_NODES) {
                f32x4 pv = *(const f32x4*)&P[colb >> 4][row][colb & 15];
                ushort4 o;
                o.x = f2bf(fmaxf(pv[0] + bv.x, 0.f));
                o.y = f2bf(fmaxf(pv[1] + bv.y, 0.f));
                o.z = f2bf(fmaxf(pv[2] + bv.z, 0.f));
                o.w = f2bf(fmaxf(pv[3] + bv.w, 0.f));
                *(ushort4*)(X1b + (size_t)node * HID + colb) = o;
            }
        }
        if (!hasNext) break;
        VWAIT0();  // features ready
        CONSUME(&Abuf[cur ^ 1][0], nlo, nhi);
        cur ^= 1;
    }
}

__global__ __launch_bounds__(512, 2) void fuse2_k(const ushort* __restrict__ X1b,
                                                  const int2* __restrict__ sedge,
                                                  const int* __restrict__ rstart,
                                                  const ushort* __restrict__ WbT2,
                                                  const float* __restrict__ b2,
                                                  float* __restrict__ out) {
    __shared__ bf16x8 Abuf[2][NREL * TILE * 8];  // 131072 B
    __shared__ float P[8][TILE][16];             // 16384 B
    int tid = threadIdx.x, bid = blockIdx.x;
    int wave = tid >> 6, lane = tid & 63;
    int mr = lane & 15, kq = lane >> 4;
    int grp = tid >> 3, l8 = tid & 7;
    int g = grp & 31, h = grp >> 5;
    int swg = (g & 7) << 4;
    int rowoff = (g << 7) + (l8 << 4);
    const ushort* xcol = X1b + l8 * 8;
    int sw = (mr & 7) << 4;
    int a00o = ((mr << 7) + (kq << 4)) ^ sw;
    int a01o = ((mr << 7) + 64 + (kq << 4)) ^ sw;
    int a10o = (((16 + mr) << 7) + (kq << 4)) ^ sw;
    int a11o = (((16 + mr) << 7) + 64 + (kq << 4)) ^ sw;

    // weights in registers: tasks {wave, wave+8} + root (wave 7 consumes)
    const ushort* wbase = WbT2 + mr * HID + kq * 8;
    bf16x8 uA0 = *(const bf16x8*)(wbase + wave * 1024);
    bf16x8 uA1 = *(const bf16x8*)(wbase + wave * 1024 + 32);
    bf16x8 uB0 = *(const bf16x8*)(wbase + (wave + 8) * 1024);
    bf16x8 uB1 = *(const bf16x8*)(wbase + (wave + 8) * 1024 + 32);
    bf16x8 wr0 = *(const bf16x8*)(wbase + 16 * 1024);
    bf16x8 wr1 = *(const bf16x8*)(wbase + 16 * 1024 + 32);
    float bc = b2[tid & 15];

    i32x2 d[16];
    bf16x8 v[16];

    int lo, hi;
    RSTART_LOAD(bid, lo, hi);
    DESC_ISSUE(lo, hi);
    VWAIT0();
    FEAT_ISSUE();
    VWAIT0();
    CONSUME(&Abuf[0][0], lo, hi);
    int cur = 0;

    for (int k = 0;; ++k) {
        int tile = bid + k * PGRID;
        int dst0 = tile * TILE;
        bool hasNext = (tile + PGRID) < NTB;
        int nlo = 0, nhi = 0;
        if (hasNext) RSTART_LOAD(tile + PGRID, nlo, nhi);
        __syncthreads();
        if (hasNext) DESC_ISSUE(nlo, nhi);
        int r0 = dst0 + mr;      if (r0 >= N_NODES) r0 = N_NODES - 1;
        int r1 = dst0 + 16 + mr; if (r1 >= N_NODES) r1 = N_NODES - 1;
        bf16x8 ra00, ra01, ra10, ra11;
        LD128A(ra00, X1b + (size_t)r0 * HID + kq * 8);
        LD128A(ra01, X1b + (size_t)r0 * HID + kq * 8 + 32);
        LD128A(ra10, X1b + (size_t)r1 * HID + kq * 8);
        LD128A(ra11, X1b + (size_t)r1 * HID + kq * 8 + 32);

        const char* Ab = (const char*)&Abuf[cur][0];
        f32x4 c0 = {0.f, 0.f, 0.f, 0.f}, c1 = {0.f, 0.f, 0.f, 0.f};
        {   // task A (t = wave): desc latency hides here
            const char* At = Ab + wave * (TILE * 128);
            bf16x8 a00 = *(const bf16x8*)(At + a00o);
            bf16x8 a01 = *(const bf16x8*)(At + a01o);
            bf16x8 a10 = *(const bf16x8*)(At + a10o);
            bf16x8 a11 = *(const bf16x8*)(At + a11o);
            c0 = MFMA16(a00, uA0, c0);
            c0 = MFMA16(a01, uA1, c0);
            c1 = MFMA16(a10, uA0, c1);
            c1 = MFMA16(a11, uA1, c1);
        }
        VWAIT0();
        if (hasNext) FEAT_ISSUE();
        {   // task B (t = wave+8)
            const char* At = Ab + (wave + 8) * (TILE * 128);
            bf16x8 a00 = *(const bf16x8*)(At + a00o);
            bf16x8 a01 = *(const bf16x8*)(At + a01o);
            bf16x8 a10 = *(const bf16x8*)(At + a10o);
            bf16x8 a11 = *(const bf16x8*)(At + a11o);
            c0 = MFMA16(a00, uB0, c0);
            c0 = MFMA16(a01, uB1, c0);
            c1 = MFMA16(a10, uB0, c1);
            c1 = MFMA16(a11, uB1, c1);
        }
        if (wave == 7) {  // root task
            c0 = MFMA16(ra00, wr0, c0);
            c0 = MFMA16(ra01, wr1, c0);
            c1 = MFMA16(ra10, wr0, c1);
            c1 = MFMA16(ra11, wr1, c1);
        }
#pragma unroll
        for (int j = 0; j < 4; ++j) {
            P[wave][kq * 4 + j][mr] = c0[j];
            P[wave][16 + kq * 4 + j][mr] = c1[j];
        }
        __syncthreads();
        {
            int row = tid >> 4, cc = tid & 15;
            int node = dst0 + row;
            if (node < N_NODES) {
                float s = P[0][row][cc] + P[1][row][cc] + P[2][row][cc] +
                          P[3][row][cc] + P[4][row][cc] + P[5][row][cc] +
                          P[6][row][cc] + P[7][row][cc] + bc;
                out[(size_t)node * NCLS + cc] = s;
            }
        }
        if (!hasNext) break;
        VWAIT0();
        CONSUME(&Abuf[cur ^ 1][0], nlo, nhi);
        cur ^= 1;
    }
}

extern "C" void kernel_launch(void* const* d_in, const int* in_sizes, int n_in,
                              void* d_out, int out_size, void* d_ws, size_t ws_size,
                              hipStream_t stream) {
    const int* ei    = (const int*)d_in[0];
    const int* et    = (const int*)d_in[1];
    const float* x   = (const float*)d_in[2];
    const float* W1  = (const float*)d_in[3];
    const float* r1  = (const float*)d_in[4];
    const float* b1  = (const float*)d_in[5];
    const float* W2  = (const float*)d_in[6];
    const float* r2  = (const float*)d_in[7];
    const float* b2  = (const float*)d_in[8];
    float* out = (float*)d_out;

    int E = in_sizes[0] / 2;
    const int* srcp = ei;
    const int* dstp = ei + E;

    int*    bcnt  = (int*)d_ws;                 // doubles as rstart after scan3
    int*    rank  = bcnt + (NBKT + 20);
    int*    bsum  = rank + E;                   // 512 ints (NSB=391 used)
    int2*   sedge = (int2*)(bsum + 512);
    ushort* WbT1  = (ushort*)(sedge + E);
    ushort* WbT2  = WbT1 + W1N;
    ushort* xb    = WbT2 + W2N;
    ushort* X1b   = xb + (size_t)N_NODES * HID;
    int*    rstart = bcnt;                      // alias (in-place scan)

    hipMemsetAsync(bcnt, 0, (NBKT + 20) * sizeof(int), stream);

    int eb = (E + 255) / 256;
    int cvtThreads = XCHUNKS + W1N + W2N;
    int cvtBlocks = (cvtThreads + 255) / 256;

    pre_k<<<eb + cvtBlocks, 256, 0, stream>>>(dstp, et, bcnt, rank, E,
                                              x, W1, r1, W2, r2, xb, WbT1, WbT2);
    scan1_k<<<NSB, 256, 0, stream>>>(bcnt, bsum);
    scan2_k<<<1, 512, 0, stream>>>(bsum, rstart, E);
    scan3_k<<<NSB, 256, 0, stream>>>(bcnt, bsum);
    scat_k<<<eb, 256, 0, stream>>>(srcp, dstp, et, rank, rstart, sedge, E);

    fuse1_k<<<PGRID, 512, 0, stream>>>(xb, sedge, rstart, WbT1, b1, X1b);
    fuse2_k<<<PGRID, 512, 0, stream>>>(X1b, sedge, rstart, WbT2, b2, out);
}